// Round 12
// baseline (214.909 us; speedup 1.0000x reference)
//
#include <hip/hip_runtime.h>

// 2-layer GCN (PyG GCNConv): self-loops, symmetric deg-norm, bias.
// CSR build (no global atomics): dst-bucket hist -> scan -> partition ->
//   per-bucket LDS {deg count, scan, rowptr/dis write, CSR scatter}.
// Compute: s1=bf16((x@W1)*dis) [MFMA] -> agg1(+b1,relu)->h bf16 ->
//          s2=bf16((h@W2)*dis) [MFMA] -> agg2(+b2) -> fp32 out.
// agg shape: wave=node, edge-slots x 16B-lane gather, unroll-4 (16 loads in
// flight/wave). int64-vs-int32 edge dtype sniffed per-block (no detect kernel).

constexpr int SCAN_CHUNK = 4096;
constexpr int NBKT = 512;          // dst buckets; npb = ceil(N/512) = 196 <= 256
constexpr int EPB  = 8192;         // edges per partition block
constexpr int CSR_CAP = 12288;     // per-bucket LDS CSR capacity (mean ~3130)

using short8 = __attribute__((ext_vector_type(8))) short;
using f32x4  = __attribute__((ext_vector_type(4))) float;

__device__ __forceinline__ unsigned short f2bf(float f) {
  unsigned u = __float_as_uint(f);
  unsigned r = (u + 0x7FFFu + ((u >> 16) & 1u)) >> 16;   // RNE
  return (unsigned short)r;
}
__device__ __forceinline__ float bf2f(unsigned short h) {
  return __uint_as_float(((unsigned)h) << 16);
}

__device__ __forceinline__ int ld_idx(const void* ei, int is64, long long i) {
  return is64 ? (int)((const long long*)ei)[i] : ((const int*)ei)[i];
}

// per-block dtype sniff: int64 edge_index => odd dwords of first 256 all zero
__device__ __forceinline__ int sniff64(const unsigned* ei, int tid) {
  unsigned v = (tid < 128) ? ei[2 * tid + 1] : 0u;
  return __syncthreads_or((int)(v != 0u)) ? 0 : 1;
}

// ---- generic hierarchical exclusive scan (bucket histogram) ----

__global__ __launch_bounds__(256) void ks_part_g(const int* __restrict__ in,
                                                 int* __restrict__ partial, int m) {
  __shared__ int red[256];
  int b = blockIdx.x, tid = threadIdx.x;
  int base = b * SCAN_CHUNK + tid * 16;
  int s = 0;
#pragma unroll
  for (int i = 0; i < 16; ++i) {
    int idx = base + i;
    if (idx < m) s += in[idx];
  }
  red[tid] = s;
  __syncthreads();
  for (int off = 128; off > 0; off >>= 1) {
    if (tid < off) red[tid] += red[tid + off];
    __syncthreads();
  }
  if (tid == 0) partial[b] = red[0];
}

__global__ __launch_bounds__(256) void k_scan_top(int* __restrict__ partial, int nparts) {
  __shared__ int sums[256];
  int tid = threadIdx.x;
  sums[tid] = (tid < nparts) ? partial[tid] : 0;
  __syncthreads();
  for (int off = 1; off < 256; off <<= 1) {
    int t = (tid >= off) ? sums[tid - off] : 0;
    __syncthreads();
    sums[tid] += t;
    __syncthreads();
  }
  if (tid < nparts) partial[tid] = (tid == 0) ? 0 : sums[tid - 1];
}

__global__ __launch_bounds__(256) void ks_write_g(const int* __restrict__ in,
                                                  const int* __restrict__ partial,
                                                  int* __restrict__ out, int m) {
  __shared__ int tsum[256];
  int b = blockIdx.x, tid = threadIdx.x;
  int base = b * SCAN_CHUNK + tid * 16;
  int vals[16];
  int s = 0;
#pragma unroll
  for (int i = 0; i < 16; ++i) {
    int idx = base + i;
    int v = (idx < m) ? in[idx] : 0;
    vals[i] = s;
    s += v;
  }
  tsum[tid] = s;
  __syncthreads();
  for (int off = 1; off < 256; off <<= 1) {
    int t = (tid >= off) ? tsum[tid - off] : 0;
    __syncthreads();
    tsum[tid] += t;
    __syncthreads();
  }
  int toff = partial[b] + ((tid == 0) ? 0 : tsum[tid - 1]);
#pragma unroll
  for (int i = 0; i < 16; ++i) {
    int idx = base + i;
    if (idx < m) out[idx] = toff + vals[i];
  }
}

// ---- bucketed partition: edges -> packed (src | dlocal<<20) grouped by bucket ----

__global__ __launch_bounds__(256) void k_hist(const void* __restrict__ ei,
                                              int* __restrict__ hist,
                                              int e, int nblk, int npb) {
  __shared__ int h[NBKT];
  int blk = blockIdx.x, tid = threadIdx.x;
  int is64 = sniff64((const unsigned*)ei, tid);
  for (int i = tid; i < NBKT; i += 256) h[i] = 0;
  __syncthreads();
  int base = blk * EPB;
  int end = base + EPB; if (end > e) end = e;
  for (int i = base + tid; i < end; i += 256) {
    int d = ld_idx(ei, is64, (long long)e + i);
    atomicAdd(&h[d / npb], 1);
  }
  __syncthreads();
  for (int i = tid; i < NBKT; i += 256)
    hist[(size_t)i * nblk + blk] = h[i];   // bucket-major
}

__global__ __launch_bounds__(256) void k_partition(const void* __restrict__ ei,
                                                   const int* __restrict__ scanned,
                                                   unsigned* __restrict__ pairbuf,
                                                   int e, int nblk, int npb) {
  __shared__ int off[NBKT];
  int blk = blockIdx.x, tid = threadIdx.x;
  int is64 = sniff64((const unsigned*)ei, tid);
  for (int i = tid; i < NBKT; i += 256)
    off[i] = scanned[(size_t)i * nblk + blk];
  __syncthreads();
  int base = blk * EPB;
  int end = base + EPB; if (end > e) end = e;
  for (int i = base + tid; i < end; i += 256) {
    int s = ld_idx(ei, is64, i);
    int d = ld_idx(ei, is64, (long long)e + i);
    int bkt = d / npb;
    int pos = atomicAdd(&off[bkt], 1);
    pairbuf[pos] = (unsigned)s | ((unsigned)(d - bkt * npb) << 20);
  }
}

// one block per bucket: LDS deg-count -> LDS scan -> rowptr/cursor/dis write
// (coalesced) -> LDS CSR scatter -> coalesced CSR write. No global atomics.
__global__ __launch_bounds__(256) void k_bucket_all(const unsigned* __restrict__ pairbuf,
                                                    const int* __restrict__ scanned,
                                                    int* __restrict__ rowptr,
                                                    int* __restrict__ cursor,
                                                    float* __restrict__ dis,
                                                    int* __restrict__ csr,
                                                    int n, int e, int npb, int nblk) {
  __shared__ int lcsr[CSR_CAP];
  __shared__ int cnt[256];     // per-node count, later scatter cursor
  __shared__ int scn[256];     // inclusive scan
  int b = blockIdx.x, tid = threadIdx.x;
  // sentinel from a block that always runs (bucket NBKT-1 may early-return!)
  if (b == 0 && tid == 0) rowptr[n] = e;
  int lo = b * npb;
  if (lo >= n) return;
  int hi = lo + npb; if (hi > n) hi = n;
  int nn = hi - lo;
  int seg_base = scanned[(size_t)b * nblk];
  int seg_end  = (b == NBKT - 1) ? e : scanned[(size_t)(b + 1) * nblk];
  int cnt_total = seg_end - seg_base;

  for (int i = tid; i < nn; i += 256) cnt[i] = 0;
  __syncthreads();
  for (int i = tid; i < cnt_total; i += 256)
    atomicAdd(&cnt[pairbuf[seg_base + i] >> 20], 1);
  __syncthreads();

  int v = (tid < nn) ? cnt[tid] : 0;    // this node's edge count (excl self-loop)
  scn[tid] = v;
  __syncthreads();
  for (int off = 1; off < 256; off <<= 1) {
    int t = (tid >= off) ? scn[tid - off] : 0;
    __syncthreads();
    scn[tid] += t;
    __syncthreads();
  }
  int start = (tid == 0) ? 0 : scn[tid - 1];   // exclusive within bucket
  if (tid < nn) {
    int node = lo + tid;
    rowptr[node] = seg_base + start;
    cursor[node] = seg_base + start;           // fallback path only
    dis[node] = rsqrtf((float)(v + 1));        // deg incl. self-loop
  }
  __syncthreads();
  if (tid < nn) cnt[tid] = start;              // scatter cursors (bucket-local)
  __syncthreads();

  if (cnt_total <= CSR_CAP) {
    for (int i = tid; i < cnt_total; i += 256) {
      unsigned p = pairbuf[seg_base + i];
      int q = atomicAdd(&cnt[p >> 20], 1);
      lcsr[q] = (int)(p & 0xFFFFFu);
    }
    __syncthreads();
    for (int i = tid; i < cnt_total; i += 256) csr[seg_base + i] = lcsr[i];
  } else {
    // statistically-unreachable overflow fallback: global atomics
    for (int i = tid; i < cnt_total; i += 256) {
      unsigned p = pairbuf[seg_base + i];
      int q = atomicAdd(&cursor[lo + (int)(p >> 20)], 1);
      csr[q] = (int)(p & 0xFFFFFu);
    }
  }
}

// ---- MFMA bf16 GEMM: S[r][c] = bf16( dis[r] * sum_k X[r][k]*W[k][c] ), K=128 ----
template <int NCOL, bool XBF16>
__global__ __launch_bounds__(256) void k_gemm_mfma(const void* __restrict__ Xv,
                                                   const float* __restrict__ W,
                                                   const float* __restrict__ dis,
                                                   unsigned short* __restrict__ S,
                                                   int nrows) {
  constexpr int ROWS = 64;
  constexpr int NCF = NCOL / 16;
  __shared__ __align__(16) unsigned short xs[ROWS * 128];
  __shared__ __align__(16) unsigned short wt[NCOL * 128];
  int tid = threadIdx.x;

  for (int id = tid; id < 128 * NCOL; id += 256) {
    int k = id / NCOL, c = id % NCOL;
    wt[(c * 128 + k) ^ ((c & 7) << 3)] = f2bf(W[id]);
  }

  int wv = tid >> 6, lane = tid & 63;
  int l16 = lane & 15, lk = lane >> 4;
  int arow = wv * 16 + l16;
  int npass = (nrows + ROWS - 1) / ROWS;

  for (int p = blockIdx.x; p < npass; p += gridDim.x) {
    int r0 = p * ROWS;
    __syncthreads();
#pragma unroll
    for (int it = 0; it < 4; ++it) {
      int id = tid + 256 * it;
      int row = id >> 4, kc = id & 15;
      int gr = r0 + row;
      unsigned short v[8];
      if (gr < nrows) {
        if (XBF16) {
          const unsigned short* xb = (const unsigned short*)Xv + (size_t)gr * 128 + kc * 8;
#pragma unroll
          for (int j = 0; j < 8; ++j) v[j] = xb[j];
        } else {
          const float4* x4 = (const float4*)Xv + (size_t)gr * 32 + kc * 2;
          float4 f0 = x4[0], f1 = x4[1];
          v[0] = f2bf(f0.x); v[1] = f2bf(f0.y); v[2] = f2bf(f0.z); v[3] = f2bf(f0.w);
          v[4] = f2bf(f1.x); v[5] = f2bf(f1.y); v[6] = f2bf(f1.z); v[7] = f2bf(f1.w);
        }
      } else {
#pragma unroll
        for (int j = 0; j < 8; ++j) v[j] = 0;
      }
      int idx = (row * 128 + kc * 8) ^ ((row & 7) << 3);
      *(short8*)&xs[idx] = *(short8*)v;
    }
    __syncthreads();

    short8 a[4];
#pragma unroll
    for (int ks = 0; ks < 4; ++ks)
      a[ks] = *(short8*)&xs[(arow * 128 + ks * 32 + lk * 8) ^ ((arow & 7) << 3)];

    f32x4 acc[NCF];
#pragma unroll
    for (int cf = 0; cf < NCF; ++cf) acc[cf] = (f32x4){0.f, 0.f, 0.f, 0.f};

#pragma unroll
    for (int cf = 0; cf < NCF; ++cf) {
      int col = cf * 16 + l16;
#pragma unroll
      for (int ks = 0; ks < 4; ++ks) {
        short8 bfr = *(short8*)&wt[(col * 128 + ks * 32 + lk * 8) ^ ((col & 7) << 3)];
        acc[cf] = __builtin_amdgcn_mfma_f32_16x16x32_bf16(a[ks], bfr, acc[cf], 0, 0, 0);
      }
    }

#pragma unroll
    for (int r = 0; r < 4; ++r) {
      int gr = r0 + wv * 16 + lk * 4 + r;
      if (gr < nrows) {
        float dv = dis[gr];
#pragma unroll
        for (int cf = 0; cf < NCF; ++cf)
          S[(size_t)gr * NCOL + cf * 16 + l16] = f2bf(acc[cf][r] * dv);
      }
    }
  }
}

// agg1: wave=node; 4 edge-slots x 16 lanes; 16B/lane; unroll-4 (16 loads in flight).
// h[i] = bf16(relu(dis_i*(s1[i]+sum_j s1[j]) + b1)), row-major bf16 out.
__global__ __launch_bounds__(256) void k_agg1(const unsigned short* __restrict__ S,
                                              const int* __restrict__ rowptr,
                                              const int* __restrict__ csr,
                                              const float* __restrict__ dis,
                                              const float* __restrict__ b1,
                                              unsigned short* __restrict__ H, int n) {
  int node = blockIdx.x * 4 + (threadIdx.x >> 6);
  if (node >= n) return;
  int lane = threadIdx.x & 63;
  int eg = lane >> 4;        // edge slot 0..3
  int cp = lane & 15;        // 16B column chunk
  float acc[8];
  if (eg == 0) {
    short8 v = *(const short8*)&S[(size_t)node * 128 + cp * 8];
#pragma unroll
    for (int k = 0; k < 8; ++k) acc[k] = bf2f((unsigned short)v[k]);
  } else {
#pragma unroll
    for (int k = 0; k < 8; ++k) acc[k] = 0.f;
  }
  int2 rp = *(const int2*)&rowptr[node];
  int e = rp.x + eg;
  for (; e + 12 < rp.y; e += 16) {
    int j0 = csr[e], j1 = csr[e + 4], j2 = csr[e + 8], j3 = csr[e + 12];
    short8 v0 = *(const short8*)&S[(size_t)j0 * 128 + cp * 8];
    short8 v1 = *(const short8*)&S[(size_t)j1 * 128 + cp * 8];
    short8 v2 = *(const short8*)&S[(size_t)j2 * 128 + cp * 8];
    short8 v3 = *(const short8*)&S[(size_t)j3 * 128 + cp * 8];
#pragma unroll
    for (int k = 0; k < 8; ++k)
      acc[k] += (bf2f((unsigned short)v0[k]) + bf2f((unsigned short)v1[k])) +
                (bf2f((unsigned short)v2[k]) + bf2f((unsigned short)v3[k]));
  }
  for (; e < rp.y; e += 4) {
    int j = csr[e];
    short8 v = *(const short8*)&S[(size_t)j * 128 + cp * 8];
#pragma unroll
    for (int k = 0; k < 8; ++k) acc[k] += bf2f((unsigned short)v[k]);
  }
#pragma unroll
  for (int k = 0; k < 8; ++k) {
    acc[k] += __shfl_xor(acc[k], 16);
    acc[k] += __shfl_xor(acc[k], 32);
  }
  if (eg == 0) {
    float d = dis[node];
    float4 bb0 = ((const float4*)b1)[cp * 2];
    float4 bb1 = ((const float4*)b1)[cp * 2 + 1];
    float bv[8] = {bb0.x, bb0.y, bb0.z, bb0.w, bb1.x, bb1.y, bb1.z, bb1.w};
    short8 o;
#pragma unroll
    for (int k = 0; k < 8; ++k)
      o[k] = (short)f2bf(fmaxf(fmaf(acc[k], d, bv[k]), 0.f));
    *(short8*)&H[(size_t)node * 128 + cp * 8] = o;
  }
}

// agg2: wave=node; 8 edge-slots x 8 lanes; 16B/lane; unroll-4 (32 loads in flight).
// out[i] = dis_i*(s2[i]+sum_j s2[j]) + b2, fp32 row-major out.
__global__ __launch_bounds__(256) void k_agg2(const unsigned short* __restrict__ S,
                                              const int* __restrict__ rowptr,
                                              const int* __restrict__ csr,
                                              const float* __restrict__ dis,
                                              const float* __restrict__ b2,
                                              float* __restrict__ O, int n) {
  int node = blockIdx.x * 4 + (threadIdx.x >> 6);
  if (node >= n) return;
  int lane = threadIdx.x & 63;
  int eg = lane >> 3;        // edge slot 0..7
  int cp = lane & 7;         // 16B column chunk (8 bf16)
  float acc[8];
  if (eg == 0) {
    short8 v = *(const short8*)&S[(size_t)node * 64 + cp * 8];
#pragma unroll
    for (int k = 0; k < 8; ++k) acc[k] = bf2f((unsigned short)v[k]);
  } else {
#pragma unroll
    for (int k = 0; k < 8; ++k) acc[k] = 0.f;
  }
  int2 rp = *(const int2*)&rowptr[node];
  int e = rp.x + eg;
  for (; e + 24 < rp.y; e += 32) {
    int j0 = csr[e], j1 = csr[e + 8], j2 = csr[e + 16], j3 = csr[e + 24];
    short8 v0 = *(const short8*)&S[(size_t)j0 * 64 + cp * 8];
    short8 v1 = *(const short8*)&S[(size_t)j1 * 64 + cp * 8];
    short8 v2 = *(const short8*)&S[(size_t)j2 * 64 + cp * 8];
    short8 v3 = *(const short8*)&S[(size_t)j3 * 64 + cp * 8];
#pragma unroll
    for (int k = 0; k < 8; ++k)
      acc[k] += (bf2f((unsigned short)v0[k]) + bf2f((unsigned short)v1[k])) +
                (bf2f((unsigned short)v2[k]) + bf2f((unsigned short)v3[k]));
  }
  for (; e < rp.y; e += 8) {
    int j = csr[e];
    short8 v = *(const short8*)&S[(size_t)j * 64 + cp * 8];
#pragma unroll
    for (int k = 0; k < 8; ++k) acc[k] += bf2f((unsigned short)v[k]);
  }
#pragma unroll
  for (int k = 0; k < 8; ++k) {
    acc[k] += __shfl_xor(acc[k], 8);
    acc[k] += __shfl_xor(acc[k], 16);
    acc[k] += __shfl_xor(acc[k], 32);
  }
  if (eg == 0) {
    float d = dis[node];
    float4 bb0 = ((const float4*)b2)[cp * 2];
    float4 bb1 = ((const float4*)b2)[cp * 2 + 1];
    float bv[8] = {bb0.x, bb0.y, bb0.z, bb0.w, bb1.x, bb1.y, bb1.z, bb1.w};
    float4 o0, o1;
    o0.x = fmaf(acc[0], d, bv[0]); o0.y = fmaf(acc[1], d, bv[1]);
    o0.z = fmaf(acc[2], d, bv[2]); o0.w = fmaf(acc[3], d, bv[3]);
    o1.x = fmaf(acc[4], d, bv[4]); o1.y = fmaf(acc[5], d, bv[5]);
    o1.z = fmaf(acc[6], d, bv[6]); o1.w = fmaf(acc[7], d, bv[7]);
    ((float4*)O)[(size_t)node * 16 + cp * 2] = o0;
    ((float4*)O)[(size_t)node * 16 + cp * 2 + 1] = o1;
  }
}

extern "C" void kernel_launch(void* const* d_in, const int* in_sizes, int n_in,
                              void* d_out, int out_size, void* d_ws, size_t ws_size,
                              hipStream_t stream) {
  const float* x  = (const float*)d_in[0];
  const void*  ei = d_in[1];
  const float* W1 = (const float*)d_in[2];
  const float* b1 = (const float*)d_in[3];
  const float* W2 = (const float*)d_in[4];
  const float* b2 = (const float*)d_in[5];
  float* out = (float*)d_out;

  const int N = in_sizes[0] / 128;
  const int E = in_sizes[1] / 2;
  const int npb  = (N + NBKT - 1) / NBKT;    // 196
  const int nblk = (E + EPB - 1) / EPB;      // 196
  const int m    = NBKT * nblk;

  char* w = (char*)d_ws;
  size_t off = 0;
  auto alloc = [&](size_t bytes) -> void* {
    void* p = (void*)(w + off);
    off += (bytes + 255) & ~(size_t)255;
    return p;
  };
  int*            rowptr  = (int*)alloc((size_t)(N + 1) * 4);
  int*            cursor  = (int*)alloc((size_t)N * 4);
  float*          dis     = (float*)alloc((size_t)N * 4);
  int*            csr     = (int*)alloc((size_t)E * 4);
  unsigned*       pairbuf = (unsigned*)alloc((size_t)E * 4);
  int*            hist    = (int*)alloc((size_t)m * 4);
  int*            scanned = (int*)alloc((size_t)m * 4);
  unsigned short* s1      = (unsigned short*)alloc((size_t)N * 128 * 2);
  unsigned short* s2      = (unsigned short*)alloc((size_t)N * 64 * 2);
  unsigned short* h       = (unsigned short*)alloc((size_t)N * 128 * 2);
  int*            partial = (int*)alloc(256 * 4);

  int npartsM = (m + SCAN_CHUNK - 1) / SCAN_CHUNK;

  k_hist<<<nblk, 256, 0, stream>>>(ei, hist, E, nblk, npb);
  ks_part_g<<<npartsM, 256, 0, stream>>>(hist, partial, m);
  k_scan_top<<<1, 256, 0, stream>>>(partial, npartsM);
  ks_write_g<<<npartsM, 256, 0, stream>>>(hist, partial, scanned, m);
  k_partition<<<nblk, 256, 0, stream>>>(ei, scanned, pairbuf, E, nblk, npb);
  k_bucket_all<<<NBKT, 256, 0, stream>>>(pairbuf, scanned, rowptr, cursor, dis, csr,
                                         N, E, npb, nblk);

  k_gemm_mfma<128, false><<<1024, 256, 0, stream>>>(x, W1, dis, s1, N);
  k_agg1<<<(N + 3) / 4, 256, 0, stream>>>(s1, rowptr, csr, dis, b1, h, N);
  k_gemm_mfma<64, true><<<1024, 256, 0, stream>>>(h, W2, dis, s2, N);
  k_agg2<<<(N + 3) / 4, 256, 0, stream>>>(s2, rowptr, csr, dis, b2, out, N);
}

// Round 13
// 205.140 us; speedup vs baseline: 1.0476x; 1.0476x over previous
//
#include <hip/hip_runtime.h>

// 2-layer GCN (PyG GCNConv): self-loops, symmetric deg-norm, bias.
// CSR build (no global atomics): dst-bucket hist -> scan -> partition ->
//   per-bucket LDS {deg count, scan, rowptr/dis write, CSR scatter}.
// Compute: s1=bf16((x@W1)*dis) [MFMA] -> agg1(+b1,relu)->h bf16 ->
//          s2=bf16((h@W2)*dis) [MFMA] -> agg2(+b2) -> fp32 out.
// agg shape (R11, best measured): wave=node, edge-slots x 16B-lane gather,
// unroll-2. agg1 pinned at ~190MB @ ~3.3TB/s = random-gather fabric ceiling.

constexpr int SCAN_CHUNK = 4096;
constexpr int NBKT = 512;          // dst buckets; npb = ceil(N/512) = 196 <= 256
constexpr int EPB  = 2048;         // edges per partition block (782 blocks)
constexpr int CSR_CAP = 12288;     // per-bucket LDS CSR capacity (mean ~3130)

using short8 = __attribute__((ext_vector_type(8))) short;
using f32x4  = __attribute__((ext_vector_type(4))) float;

__device__ __forceinline__ unsigned short f2bf(float f) {
  unsigned u = __float_as_uint(f);
  unsigned r = (u + 0x7FFFu + ((u >> 16) & 1u)) >> 16;   // RNE
  return (unsigned short)r;
}
__device__ __forceinline__ float bf2f(unsigned short h) {
  return __uint_as_float(((unsigned)h) << 16);
}

__device__ __forceinline__ int ld_idx(const void* ei, int is64, long long i) {
  return is64 ? (int)((const long long*)ei)[i] : ((const int*)ei)[i];
}

// per-block dtype sniff: int64 edge_index => odd dwords of first 256 all zero
__device__ __forceinline__ int sniff64(const unsigned* ei, int tid) {
  unsigned v = (tid < 128) ? ei[2 * tid + 1] : 0u;
  return __syncthreads_or((int)(v != 0u)) ? 0 : 1;
}

// ---- hierarchical exclusive scan over hist (2 kernels; write pass computes
//      its own cross-block prefix from raw partials) ----

__global__ __launch_bounds__(256) void ks_part_g(const int* __restrict__ in,
                                                 int* __restrict__ partial, int m) {
  __shared__ int red[256];
  int b = blockIdx.x, tid = threadIdx.x;
  int base = b * SCAN_CHUNK + tid * 16;
  int s = 0;
#pragma unroll
  for (int i = 0; i < 16; ++i) {
    int idx = base + i;
    if (idx < m) s += in[idx];
  }
  red[tid] = s;
  __syncthreads();
  for (int off = 128; off > 0; off >>= 1) {
    if (tid < off) red[tid] += red[tid + off];
    __syncthreads();
  }
  if (tid == 0) partial[b] = red[0];
}

__global__ __launch_bounds__(256) void ks_write_g(const int* __restrict__ in,
                                                  const int* __restrict__ partial,
                                                  int* __restrict__ out, int m) {
  __shared__ int red[256];
  __shared__ int tsum[256];
  int b = blockIdx.x, tid = threadIdx.x;
  // cross-block exclusive prefix: sum partial[0..b)
  int pb = 0;
  for (int j = tid; j < b; j += 256) pb += partial[j];
  red[tid] = pb;
  __syncthreads();
  for (int off = 128; off > 0; off >>= 1) {
    if (tid < off) red[tid] += red[tid + off];
    __syncthreads();
  }
  int block_base = red[0];
  __syncthreads();

  int base = b * SCAN_CHUNK + tid * 16;
  int vals[16];
  int s = 0;
#pragma unroll
  for (int i = 0; i < 16; ++i) {
    int idx = base + i;
    int v = (idx < m) ? in[idx] : 0;
    vals[i] = s;
    s += v;
  }
  tsum[tid] = s;
  __syncthreads();
  for (int off = 1; off < 256; off <<= 1) {
    int t = (tid >= off) ? tsum[tid - off] : 0;
    __syncthreads();
    tsum[tid] += t;
    __syncthreads();
  }
  int toff = block_base + ((tid == 0) ? 0 : tsum[tid - 1]);
#pragma unroll
  for (int i = 0; i < 16; ++i) {
    int idx = base + i;
    if (idx < m) out[idx] = toff + vals[i];
  }
}

// ---- bucketed partition: edges -> packed (src | dlocal<<20) grouped by bucket ----

__global__ __launch_bounds__(256) void k_hist(const void* __restrict__ ei,
                                              int* __restrict__ hist,
                                              int e, int nblk, int npb) {
  __shared__ int h[NBKT];
  int blk = blockIdx.x, tid = threadIdx.x;
  int is64 = sniff64((const unsigned*)ei, tid);
  for (int i = tid; i < NBKT; i += 256) h[i] = 0;
  __syncthreads();
  int base = blk * EPB;
  int end = base + EPB; if (end > e) end = e;
  for (int i = base + tid; i < end; i += 256) {
    int d = ld_idx(ei, is64, (long long)e + i);
    atomicAdd(&h[d / npb], 1);
  }
  __syncthreads();
  for (int i = tid; i < NBKT; i += 256)
    hist[(size_t)i * nblk + blk] = h[i];   // bucket-major
}

__global__ __launch_bounds__(256) void k_partition(const void* __restrict__ ei,
                                                   const int* __restrict__ scanned,
                                                   unsigned* __restrict__ pairbuf,
                                                   int e, int nblk, int npb) {
  __shared__ int off[NBKT];
  int blk = blockIdx.x, tid = threadIdx.x;
  int is64 = sniff64((const unsigned*)ei, tid);
  for (int i = tid; i < NBKT; i += 256)
    off[i] = scanned[(size_t)i * nblk + blk];
  __syncthreads();
  int base = blk * EPB;
  int end = base + EPB; if (end > e) end = e;
  for (int i = base + tid; i < end; i += 256) {
    int s = ld_idx(ei, is64, i);
    int d = ld_idx(ei, is64, (long long)e + i);
    int bkt = d / npb;
    int pos = atomicAdd(&off[bkt], 1);
    pairbuf[pos] = (unsigned)s | ((unsigned)(d - bkt * npb) << 20);
  }
}

// one block per bucket: LDS deg-count -> LDS scan -> rowptr/cursor/dis write
// (coalesced) -> LDS CSR scatter -> coalesced CSR write. No global atomics.
__global__ __launch_bounds__(256) void k_bucket_all(const unsigned* __restrict__ pairbuf,
                                                    const int* __restrict__ scanned,
                                                    int* __restrict__ rowptr,
                                                    int* __restrict__ cursor,
                                                    float* __restrict__ dis,
                                                    int* __restrict__ csr,
                                                    int n, int e, int npb, int nblk) {
  __shared__ int lcsr[CSR_CAP];
  __shared__ int cnt[256];     // per-node count, later scatter cursor
  __shared__ int scn[256];     // inclusive scan
  int b = blockIdx.x, tid = threadIdx.x;
  // sentinel from a block that always runs (bucket NBKT-1 may early-return!)
  if (b == 0 && tid == 0) rowptr[n] = e;
  int lo = b * npb;
  if (lo >= n) return;
  int hi = lo + npb; if (hi > n) hi = n;
  int nn = hi - lo;
  int seg_base = scanned[(size_t)b * nblk];
  int seg_end  = (b == NBKT - 1) ? e : scanned[(size_t)(b + 1) * nblk];
  int cnt_total = seg_end - seg_base;

  for (int i = tid; i < nn; i += 256) cnt[i] = 0;
  __syncthreads();
  for (int i = tid; i < cnt_total; i += 256)
    atomicAdd(&cnt[pairbuf[seg_base + i] >> 20], 1);
  __syncthreads();

  int v = (tid < nn) ? cnt[tid] : 0;    // this node's edge count (excl self-loop)
  scn[tid] = v;
  __syncthreads();
  for (int off = 1; off < 256; off <<= 1) {
    int t = (tid >= off) ? scn[tid - off] : 0;
    __syncthreads();
    scn[tid] += t;
    __syncthreads();
  }
  int start = (tid == 0) ? 0 : scn[tid - 1];   // exclusive within bucket
  if (tid < nn) {
    int node = lo + tid;
    rowptr[node] = seg_base + start;
    cursor[node] = seg_base + start;           // fallback path only
    dis[node] = rsqrtf((float)(v + 1));        // deg incl. self-loop
  }
  __syncthreads();
  if (tid < nn) cnt[tid] = start;              // scatter cursors (bucket-local)
  __syncthreads();

  if (cnt_total <= CSR_CAP) {
    for (int i = tid; i < cnt_total; i += 256) {
      unsigned p = pairbuf[seg_base + i];
      int q = atomicAdd(&cnt[p >> 20], 1);
      lcsr[q] = (int)(p & 0xFFFFFu);
    }
    __syncthreads();
    for (int i = tid; i < cnt_total; i += 256) csr[seg_base + i] = lcsr[i];
  } else {
    // statistically-unreachable overflow fallback: global atomics
    for (int i = tid; i < cnt_total; i += 256) {
      unsigned p = pairbuf[seg_base + i];
      int q = atomicAdd(&cursor[lo + (int)(p >> 20)], 1);
      csr[q] = (int)(p & 0xFFFFFu);
    }
  }
}

// ---- MFMA bf16 GEMM: S[r][c] = bf16( dis[r] * sum_k X[r][k]*W[k][c] ), K=128 ----
template <int NCOL, bool XBF16>
__global__ __launch_bounds__(256) void k_gemm_mfma(const void* __restrict__ Xv,
                                                   const float* __restrict__ W,
                                                   const float* __restrict__ dis,
                                                   unsigned short* __restrict__ S,
                                                   int nrows) {
  constexpr int ROWS = 64;
  constexpr int NCF = NCOL / 16;
  __shared__ __align__(16) unsigned short xs[ROWS * 128];
  __shared__ __align__(16) unsigned short wt[NCOL * 128];
  int tid = threadIdx.x;

  for (int id = tid; id < 128 * NCOL; id += 256) {
    int k = id / NCOL, c = id % NCOL;
    wt[(c * 128 + k) ^ ((c & 7) << 3)] = f2bf(W[id]);
  }

  int wv = tid >> 6, lane = tid & 63;
  int l16 = lane & 15, lk = lane >> 4;
  int arow = wv * 16 + l16;
  int npass = (nrows + ROWS - 1) / ROWS;

  for (int p = blockIdx.x; p < npass; p += gridDim.x) {
    int r0 = p * ROWS;
    __syncthreads();
#pragma unroll
    for (int it = 0; it < 4; ++it) {
      int id = tid + 256 * it;
      int row = id >> 4, kc = id & 15;
      int gr = r0 + row;
      unsigned short v[8];
      if (gr < nrows) {
        if (XBF16) {
          const unsigned short* xb = (const unsigned short*)Xv + (size_t)gr * 128 + kc * 8;
#pragma unroll
          for (int j = 0; j < 8; ++j) v[j] = xb[j];
        } else {
          const float4* x4 = (const float4*)Xv + (size_t)gr * 32 + kc * 2;
          float4 f0 = x4[0], f1 = x4[1];
          v[0] = f2bf(f0.x); v[1] = f2bf(f0.y); v[2] = f2bf(f0.z); v[3] = f2bf(f0.w);
          v[4] = f2bf(f1.x); v[5] = f2bf(f1.y); v[6] = f2bf(f1.z); v[7] = f2bf(f1.w);
        }
      } else {
#pragma unroll
        for (int j = 0; j < 8; ++j) v[j] = 0;
      }
      int idx = (row * 128 + kc * 8) ^ ((row & 7) << 3);
      *(short8*)&xs[idx] = *(short8*)v;
    }
    __syncthreads();

    short8 a[4];
#pragma unroll
    for (int ks = 0; ks < 4; ++ks)
      a[ks] = *(short8*)&xs[(arow * 128 + ks * 32 + lk * 8) ^ ((arow & 7) << 3)];

    f32x4 acc[NCF];
#pragma unroll
    for (int cf = 0; cf < NCF; ++cf) acc[cf] = (f32x4){0.f, 0.f, 0.f, 0.f};

#pragma unroll
    for (int cf = 0; cf < NCF; ++cf) {
      int col = cf * 16 + l16;
#pragma unroll
      for (int ks = 0; ks < 4; ++ks) {
        short8 bfr = *(short8*)&wt[(col * 128 + ks * 32 + lk * 8) ^ ((col & 7) << 3)];
        acc[cf] = __builtin_amdgcn_mfma_f32_16x16x32_bf16(a[ks], bfr, acc[cf], 0, 0, 0);
      }
    }

#pragma unroll
    for (int r = 0; r < 4; ++r) {
      int gr = r0 + wv * 16 + lk * 4 + r;
      if (gr < nrows) {
        float dv = dis[gr];
#pragma unroll
        for (int cf = 0; cf < NCF; ++cf)
          S[(size_t)gr * NCOL + cf * 16 + l16] = f2bf(acc[cf][r] * dv);
      }
    }
  }
}

// agg1: wave=node; 4 edge-slots x 16 lanes; each lane loads 16B (8 bf16 cols).
// h[i] = bf16(relu(dis_i*(s1[i]+sum_j s1[j]) + b1)), row-major bf16 out.
__global__ __launch_bounds__(256) void k_agg1(const unsigned short* __restrict__ S,
                                              const int* __restrict__ rowptr,
                                              const int* __restrict__ csr,
                                              const float* __restrict__ dis,
                                              const float* __restrict__ b1,
                                              unsigned short* __restrict__ H, int n) {
  int node = blockIdx.x * 4 + (threadIdx.x >> 6);
  if (node >= n) return;
  int lane = threadIdx.x & 63;
  int eg = lane >> 4;        // edge slot 0..3
  int cp = lane & 15;        // 16B column chunk
  float acc[8];
  if (eg == 0) {
    short8 v = *(const short8*)&S[(size_t)node * 128 + cp * 8];
#pragma unroll
    for (int k = 0; k < 8; ++k) acc[k] = bf2f((unsigned short)v[k]);
  } else {
#pragma unroll
    for (int k = 0; k < 8; ++k) acc[k] = 0.f;
  }
  int2 rp = *(const int2*)&rowptr[node];
  int e = rp.x + eg;
  for (; e + 4 < rp.y; e += 8) {
    int j0 = csr[e], j1 = csr[e + 4];
    short8 v0 = *(const short8*)&S[(size_t)j0 * 128 + cp * 8];
    short8 v1 = *(const short8*)&S[(size_t)j1 * 128 + cp * 8];
#pragma unroll
    for (int k = 0; k < 8; ++k)
      acc[k] += bf2f((unsigned short)v0[k]) + bf2f((unsigned short)v1[k]);
  }
  if (e < rp.y) {
    int j = csr[e];
    short8 v = *(const short8*)&S[(size_t)j * 128 + cp * 8];
#pragma unroll
    for (int k = 0; k < 8; ++k) acc[k] += bf2f((unsigned short)v[k]);
  }
#pragma unroll
  for (int k = 0; k < 8; ++k) {
    acc[k] += __shfl_xor(acc[k], 16);
    acc[k] += __shfl_xor(acc[k], 32);
  }
  if (eg == 0) {
    float d = dis[node];
    float4 bb0 = ((const float4*)b1)[cp * 2];
    float4 bb1 = ((const float4*)b1)[cp * 2 + 1];
    float bv[8] = {bb0.x, bb0.y, bb0.z, bb0.w, bb1.x, bb1.y, bb1.z, bb1.w};
    short8 o;
#pragma unroll
    for (int k = 0; k < 8; ++k)
      o[k] = (short)f2bf(fmaxf(fmaf(acc[k], d, bv[k]), 0.f));
    *(short8*)&H[(size_t)node * 128 + cp * 8] = o;
  }
}

// agg2: wave=node; 8 edge-slots x 8 lanes; 16B/lane covers the 128B row.
// out[i] = dis_i*(s2[i]+sum_j s2[j]) + b2, fp32 row-major out.
__global__ __launch_bounds__(256) void k_agg2(const unsigned short* __restrict__ S,
                                              const int* __restrict__ rowptr,
                                              const int* __restrict__ csr,
                                              const float* __restrict__ dis,
                                              const float* __restrict__ b2,
                                              float* __restrict__ O, int n) {
  int node = blockIdx.x * 4 + (threadIdx.x >> 6);
  if (node >= n) return;
  int lane = threadIdx.x & 63;
  int eg = lane >> 3;        // edge slot 0..7
  int cp = lane & 7;         // 16B column chunk (8 bf16)
  float acc[8];
  if (eg == 0) {
    short8 v = *(const short8*)&S[(size_t)node * 64 + cp * 8];
#pragma unroll
    for (int k = 0; k < 8; ++k) acc[k] = bf2f((unsigned short)v[k]);
  } else {
#pragma unroll
    for (int k = 0; k < 8; ++k) acc[k] = 0.f;
  }
  int2 rp = *(const int2*)&rowptr[node];
  int e = rp.x + eg;
  for (; e + 8 < rp.y; e += 16) {
    int j0 = csr[e], j1 = csr[e + 8];
    short8 v0 = *(const short8*)&S[(size_t)j0 * 64 + cp * 8];
    short8 v1 = *(const short8*)&S[(size_t)j1 * 64 + cp * 8];
#pragma unroll
    for (int k = 0; k < 8; ++k)
      acc[k] += bf2f((unsigned short)v0[k]) + bf2f((unsigned short)v1[k]);
  }
  if (e < rp.y) {
    int j = csr[e];
    short8 v = *(const short8*)&S[(size_t)j * 64 + cp * 8];
#pragma unroll
    for (int k = 0; k < 8; ++k) acc[k] += bf2f((unsigned short)v[k]);
  }
#pragma unroll
  for (int k = 0; k < 8; ++k) {
    acc[k] += __shfl_xor(acc[k], 8);
    acc[k] += __shfl_xor(acc[k], 16);
    acc[k] += __shfl_xor(acc[k], 32);
  }
  if (eg == 0) {
    float d = dis[node];
    float4 bb0 = ((const float4*)b2)[cp * 2];
    float4 bb1 = ((const float4*)b2)[cp * 2 + 1];
    float bv[8] = {bb0.x, bb0.y, bb0.z, bb0.w, bb1.x, bb1.y, bb1.z, bb1.w};
    float4 o0, o1;
    o0.x = fmaf(acc[0], d, bv[0]); o0.y = fmaf(acc[1], d, bv[1]);
    o0.z = fmaf(acc[2], d, bv[2]); o0.w = fmaf(acc[3], d, bv[3]);
    o1.x = fmaf(acc[4], d, bv[4]); o1.y = fmaf(acc[5], d, bv[5]);
    o1.z = fmaf(acc[6], d, bv[6]); o1.w = fmaf(acc[7], d, bv[7]);
    ((float4*)O)[(size_t)node * 16 + cp * 2] = o0;
    ((float4*)O)[(size_t)node * 16 + cp * 2 + 1] = o1;
  }
}

extern "C" void kernel_launch(void* const* d_in, const int* in_sizes, int n_in,
                              void* d_out, int out_size, void* d_ws, size_t ws_size,
                              hipStream_t stream) {
  const float* x  = (const float*)d_in[0];
  const void*  ei = d_in[1];
  const float* W1 = (const float*)d_in[2];
  const float* b1 = (const float*)d_in[3];
  const float* W2 = (const float*)d_in[4];
  const float* b2 = (const float*)d_in[5];
  float* out = (float*)d_out;

  const int N = in_sizes[0] / 128;
  const int E = in_sizes[1] / 2;
  const int npb  = (N + NBKT - 1) / NBKT;    // 196
  const int nblk = (E + EPB - 1) / EPB;      // 782
  const int m    = NBKT * nblk;              // ~400K

  char* w = (char*)d_ws;
  size_t off = 0;
  auto alloc = [&](size_t bytes) -> void* {
    void* p = (void*)(w + off);
    off += (bytes + 255) & ~(size_t)255;
    return p;
  };
  int*            rowptr  = (int*)alloc((size_t)(N + 1) * 4);
  int*            cursor  = (int*)alloc((size_t)N * 4);
  float*          dis     = (float*)alloc((size_t)N * 4);
  int*            csr     = (int*)alloc((size_t)E * 4);
  unsigned*       pairbuf = (unsigned*)alloc((size_t)E * 4);
  int*            hist    = (int*)alloc((size_t)m * 4);
  int*            scanned = (int*)alloc((size_t)m * 4);
  unsigned short* s1      = (unsigned short*)alloc((size_t)N * 128 * 2);
  unsigned short* s2      = (unsigned short*)alloc((size_t)N * 64 * 2);
  unsigned short* h       = (unsigned short*)alloc((size_t)N * 128 * 2);
  int*            partial = (int*)alloc(256 * 4);

  int npartsM = (m + SCAN_CHUNK - 1) / SCAN_CHUNK;   // ~98 <= 256

  k_hist<<<nblk, 256, 0, stream>>>(ei, hist, E, nblk, npb);
  ks_part_g<<<npartsM, 256, 0, stream>>>(hist, partial, m);
  ks_write_g<<<npartsM, 256, 0, stream>>>(hist, partial, scanned, m);
  k_partition<<<nblk, 256, 0, stream>>>(ei, scanned, pairbuf, E, nblk, npb);
  k_bucket_all<<<NBKT, 256, 0, stream>>>(pairbuf, scanned, rowptr, cursor, dis, csr,
                                         N, E, npb, nblk);

  k_gemm_mfma<128, false><<<1024, 256, 0, stream>>>(x, W1, dis, s1, N);
  k_agg1<<<(N + 3) / 4, 256, 0, stream>>>(s1, rowptr, csr, dis, b1, h, N);
  k_gemm_mfma<64, true><<<1024, 256, 0, stream>>>(h, W2, dis, s2, N);
  k_agg2<<<(N + 3) / 4, 256, 0, stream>>>(s2, rowptr, csr, dis, b2, out, N);
}